// Round 5
// baseline (1683.104 us; speedup 1.0000x reference)
//
#include <hip/hip_runtime.h>

#define N_NODES 50000
#define N_EDGES 500000
#define F_INDIM 388
#define H_HEADS 8
#define DD1 64
#define DD2 128
#define EDIM 16
#define HIDN 32

#define M_PAD 50048   // 391*128
#define K1_PAD 416    // 388 padded to mult of 32

typedef unsigned short u16;
typedef unsigned int u32;
typedef __attribute__((ext_vector_type(8))) short bf16x8;
typedef __attribute__((ext_vector_type(4))) float f32x4;

static __device__ __forceinline__ float bfu2f(u32 lo16) {
  union { u32 u; float f; } c;
  c.u = lo16 << 16;
  return c.f;
}
static __device__ __forceinline__ u16 f2bf(float f) {
  union { float f; u32 u; } c;
  c.f = f;
  u32 u = c.u + 0x7fffu + ((c.u >> 16) & 1u);
  return (u16)(u >> 16);
}

static __device__ __forceinline__ float waveSum(float v) {
#pragma unroll
  for (int off = 32; off > 0; off >>= 1) v += __shfl_xor(v, off, 64);
  return v;
}
static __device__ __forceinline__ void waveSum4(float& a, float& b, float& c, float& d) {
#pragma unroll
  for (int off = 32; off > 0; off >>= 1) {
    a += __shfl_xor(a, off, 64);
    b += __shfl_xor(b, off, 64);
    c += __shfl_xor(c, off, 64);
    d += __shfl_xor(d, off, 64);
  }
}

static __device__ __forceinline__ void gl_lds16(const void* g, void* l) {
  __builtin_amdgcn_global_load_lds((const __attribute__((address_space(1))) u32*)g,
                                   (__attribute__((address_space(3))) u32*)l, 16, 0, 0);
}

__global__ void k_zero(float* __restrict__ out, int n) {
  int i = blockIdx.x * blockDim.x + threadIdx.x;
  if (i < n) out[i] = 0.f;
}

// ---------------- CSR build ----------------
__global__ void k_hist(const int* __restrict__ dst, int* __restrict__ deg) {
  int e = blockIdx.x * blockDim.x + threadIdx.x;
  if (e < N_EDGES) atomicAdd(&deg[dst[e]], 1);
}

__global__ __launch_bounds__(1024) void k_scan(const int* __restrict__ deg,
                                               int* __restrict__ row_start) {
  __shared__ int wsum[16];
  __shared__ int carry_s;
  int tid = threadIdx.x;
  int lane = tid & 63, wv = tid >> 6;
  if (tid == 0) carry_s = 0;
  __syncthreads();
  for (int base = 0; base < N_NODES; base += 1024) {
    int i = base + tid;
    int v = (i < N_NODES) ? deg[i] : 0;
    int inc = v;
#pragma unroll
    for (int off = 1; off < 64; off <<= 1) {
      int t = __shfl_up(inc, off, 64);
      if (lane >= off) inc += t;
    }
    if (lane == 63) wsum[wv] = inc;
    __syncthreads();
    if (wv == 0 && lane < 16) {
      int s = wsum[lane];
#pragma unroll
      for (int off = 1; off < 16; off <<= 1) {
        int t = __shfl_up(s, off, 64);
        if (lane >= off) s += t;
      }
      wsum[lane] = s;
    }
    __syncthreads();
    int add = (wv > 0) ? wsum[wv - 1] : 0;
    int ex = carry_s + add + inc - v;
    if (i < N_NODES) row_start[i] = ex;
    __syncthreads();
    if (tid == 0) carry_s += wsum[15];
    __syncthreads();
  }
  if (threadIdx.x == 0) row_start[N_NODES] = carry_s;
}

__global__ void k_scatter(const int* __restrict__ dst, const int* __restrict__ src,
                          const int* __restrict__ row_start, int* __restrict__ cursor,
                          int* __restrict__ eid, int* __restrict__ srcp) {
  int e = blockIdx.x * blockDim.x + threadIdx.x;
  if (e < N_EDGES) {
    int d = dst[e];
    int pos = row_start[d] + atomicAdd(&cursor[d], 1);
    eid[pos] = e;
    srcp[pos] = src[e];
  }
}

// ---------------- loop_attr: la[n][16] = mean of ea rows over in-edges ----------------
__global__ __launch_bounds__(256) void k_la(const float* __restrict__ ea,
                                            const int* __restrict__ eid,
                                            const int* __restrict__ row_start,
                                            float* __restrict__ la) {
  int node = blockIdx.x * 16 + (threadIdx.x >> 4);
  int k = threadIdx.x & 15;
  if (node >= N_NODES) return;
  int r0 = row_start[node], r1 = row_start[node + 1];
  float s = 0.f;
  for (int i = r0; i < r1; ++i) s += ea[(size_t)eid[i] * EDIM + k];
  la[node * EDIM + k] = s / (float)max(r1 - r0, 1);
}

// ---------------- conversions ----------------
__global__ void k_cvt_x(const float* __restrict__ x, u16* __restrict__ xb) {
  long t = (long)blockIdx.x * 256 + threadIdx.x;
  if (t >= (long)M_PAD * K1_PAD) return;
  int row = (int)(t / K1_PAD);
  int col = (int)(t % K1_PAD);
  float v = (row < N_NODES && col < F_INDIM) ? x[(size_t)row * F_INDIM + col] : 0.f;
  xb[t] = f2bf(v);
}

// W fp32 [K][N] -> WT bf16 [N][Kp], zero pad k>=K
__global__ void k_cvt_wT(const float* __restrict__ W, u16* __restrict__ WT, int K, int N, int Kp) {
  int t = blockIdx.x * 256 + threadIdx.x;
  if (t >= N * Kp) return;
  int n = t / Kp, k = t % Kp;
  WT[t] = f2bf(k < K ? W[(size_t)k * N + n] : 0.f);
}

__global__ void k_cvt(const float* __restrict__ W, u16* __restrict__ O, int n) {
  int t = blockIdx.x * 256 + threadIdx.x;
  if (t < n) O[t] = f2bf(W[t]);
}

// ---------------- MFMA bf16 GEMM: C[M,Nd] = A[M,K] @ BT[Nd,K]^T ----------------
template <bool CF32>
__global__ __launch_bounds__(256) void gemm_mfma(const u16* __restrict__ A,
                                                 const u16* __restrict__ BT,
                                                 void* __restrict__ Cv, int M, int Nd, int K,
                                                 int lda, int ldb) {
  __shared__ u16 As[128 * 32];
  __shared__ u16 Bs[128 * 32];
  int tid = threadIdx.x;
  int lane = tid & 63;
  int wv = tid >> 6;
  int m_base = blockIdx.y * 128;
  int n_base = blockIdx.x * 128;
  int wrow = (wv >> 1) * 64;
  int wcol = (wv & 1) * 64;
  f32x4 acc[4][4];
#pragma unroll
  for (int i = 0; i < 4; ++i)
#pragma unroll
    for (int j = 0; j < 4; ++j)
#pragma unroll
      for (int r = 0; r < 4; ++r) acc[i][j][r] = 0.f;

  for (int k0 = 0; k0 < K; k0 += 32) {
    __syncthreads();
#pragma unroll
    for (int it = 0; it < 2; ++it) {
      int t = it * 256 + tid;
      int row = t >> 2;
      int kc = (t & 3) * 8;
      gl_lds16(A + (size_t)(m_base + row) * lda + k0 + kc, As + (size_t)(it * 256 + wv * 64) * 8);
      gl_lds16(BT + (size_t)(n_base + row) * ldb + k0 + kc, Bs + (size_t)(it * 256 + wv * 64) * 8);
    }
    __syncthreads();
    bf16x8 af[4], bfr[4];
#pragma unroll
    for (int i = 0; i < 4; ++i) {
      int r = wrow + i * 16 + (lane & 15);
      af[i] = *(const bf16x8*)(As + r * 32 + (lane >> 4) * 8);
    }
#pragma unroll
    for (int j = 0; j < 4; ++j) {
      int r = wcol + j * 16 + (lane & 15);
      bfr[j] = *(const bf16x8*)(Bs + r * 32 + (lane >> 4) * 8);
    }
#pragma unroll
    for (int i = 0; i < 4; ++i)
#pragma unroll
      for (int j = 0; j < 4; ++j)
        acc[i][j] = __builtin_amdgcn_mfma_f32_16x16x32_bf16(af[i], bfr[j], acc[i][j], 0, 0, 0);
  }
#pragma unroll
  for (int i = 0; i < 4; ++i) {
    int grow_base = m_base + wrow + i * 16 + (lane >> 4) * 4;
#pragma unroll
    for (int j = 0; j < 4; ++j) {
      int gcol = n_base + wcol + j * 16 + (lane & 15);
#pragma unroll
      for (int r = 0; r < 4; ++r) {
        int grow = grow_base + r;
        if (grow < M) {
          float v = acc[i][j][r];
          if (CF32)
            ((float*)Cv)[(size_t)grow * Nd + gcol] = v;
          else
            ((u16*)Cv)[(size_t)grow * Nd + gcol] = f2bf(v);
        }
      }
    }
  }
}

// ---------------- GAT layer 1 (D=64, concat) ----------------
// xlr: [n][xl(512)|xr(512)] bf16. lrelu folded: p = 0.6a*z + 0.4a*|z|. No LDS/barriers.
__global__ __launch_bounds__(512) void k_gat1(
    const u16* __restrict__ xlr, const float* __restrict__ ea, const float* __restrict__ We,
    const float* __restrict__ att, const float* __restrict__ bias, const int* __restrict__ srcp,
    const int* __restrict__ eid, const int* __restrict__ row_start, const float* __restrict__ la,
    u16* __restrict__ out) {
  int n = blockIdx.x;
  int col = threadIdx.x;  // 0..511, wave == head
  int r0 = row_start[n], r1 = row_start[n + 1];
  float Wc[EDIM];
#pragma unroll
  for (int k = 0; k < EDIM; ++k) Wc[k] = We[k * 512 + col];
  float a = att[col];
  float attA = 0.6f * a, attB = 0.4f * a;
  float xrd = bfu2f(xlr[(size_t)n * 1024 + 512 + col]);
  float xlself = bfu2f(xlr[(size_t)n * 1024 + col]);

  auto escore = [&](int e, float xv) -> float {
    const float4* ea4 = (const float4*)(ea + (size_t)e * EDIM);
    float4 v0 = ea4[0], v1 = ea4[1], v2 = ea4[2], v3 = ea4[3];
    float t = v0.x * Wc[0];
    t = fmaf(v0.y, Wc[1], t);
    t = fmaf(v0.z, Wc[2], t);
    t = fmaf(v0.w, Wc[3], t);
    t = fmaf(v1.x, Wc[4], t);
    t = fmaf(v1.y, Wc[5], t);
    t = fmaf(v1.z, Wc[6], t);
    t = fmaf(v1.w, Wc[7], t);
    t = fmaf(v2.x, Wc[8], t);
    t = fmaf(v2.y, Wc[9], t);
    t = fmaf(v2.z, Wc[10], t);
    t = fmaf(v2.w, Wc[11], t);
    t = fmaf(v3.x, Wc[12], t);
    t = fmaf(v3.y, Wc[13], t);
    t = fmaf(v3.z, Wc[14], t);
    t = fmaf(v3.w, Wc[15], t);
    float z = xv + xrd + t;
    return fmaf(attA, z, attB * fabsf(z));
  };

  float acc = 0.f, denom = 0.f;
  int iend = r0 + ((r1 - r0) & ~3);
  int i = r0;
  if (i < iend) {
    int E[4], S[4];
    float X[4];
#pragma unroll
    for (int r = 0; r < 4; ++r) {
      E[r] = __builtin_amdgcn_readfirstlane(eid[i + r]);
      S[r] = __builtin_amdgcn_readfirstlane(srcp[i + r]);
    }
#pragma unroll
    for (int r = 0; r < 4; ++r) X[r] = bfu2f(xlr[(size_t)S[r] * 1024 + col]);
    while (i < iend) {
      int inext = i + 4;
      int En[4], Sn[4];
      float Xn[4];
      bool more = inext < iend;
      if (more) {
#pragma unroll
        for (int r = 0; r < 4; ++r) {
          En[r] = __builtin_amdgcn_readfirstlane(eid[inext + r]);
          Sn[r] = __builtin_amdgcn_readfirstlane(srcp[inext + r]);
        }
#pragma unroll
        for (int r = 0; r < 4; ++r) Xn[r] = bfu2f(xlr[(size_t)Sn[r] * 1024 + col]);
      }
      float p0 = escore(E[0], X[0]);
      float p1 = escore(E[1], X[1]);
      float p2 = escore(E[2], X[2]);
      float p3 = escore(E[3], X[3]);
      waveSum4(p0, p1, p2, p3);
      float w0 = __expf(p0), w1 = __expf(p1), w2 = __expf(p2), w3 = __expf(p3);
      acc = fmaf(w0, X[0], acc);
      acc = fmaf(w1, X[1], acc);
      acc = fmaf(w2, X[2], acc);
      acc = fmaf(w3, X[3], acc);
      denom += (w0 + w1) + (w2 + w3);
      if (more) {
#pragma unroll
        for (int r = 0; r < 4; ++r) {
          E[r] = En[r];
          S[r] = Sn[r];
          X[r] = Xn[r];
        }
      }
      i = inext;
    }
  }
  for (; i < r1; ++i) {
    int e = eid[i], s = srcp[i];
    float xv = bfu2f(xlr[(size_t)s * 1024 + col]);
    float p = waveSum(escore(e, xv));
    float w = __expf(p);
    acc = fmaf(w, xv, acc);
    denom += w;
  }
  // self loop via precomputed la
  float ee = 0.f;
#pragma unroll
  for (int k = 0; k < EDIM; ++k) ee = fmaf(la[n * EDIM + k], Wc[k], ee);
  float z = xlself + xrd + ee;
  float sc = waveSum(fmaf(attA, z, attB * fabsf(z)));
  float w = __expf(sc);
  acc = fmaf(w, xlself, acc);
  denom += w;
  out[(size_t)n * 512 + col] = f2bf(tanhf(acc / denom + bias[col]));
}

// ---------------- GAT layer 2 (D=128, mean heads) ----------------
// xlr: [n][xl(1024)|xr(1024)] bf16.
__global__ __launch_bounds__(512) void k_gat2(
    const u16* __restrict__ xlr, const float* __restrict__ ea, const float* __restrict__ We,
    const float* __restrict__ att, const float* __restrict__ bias, const int* __restrict__ srcp,
    const int* __restrict__ eid, const int* __restrict__ row_start, const float* __restrict__ la,
    u16* __restrict__ out) {
  int n = blockIdx.x;
  int tid = threadIdx.x;
  int lane = tid & 63;
  int h = tid >> 6;
  __shared__ float hsum[H_HEADS][DD2];
  int r0 = row_start[n], r1 = row_start[n + 1];
  int col = h * DD2 + lane * 2;
  float Wcx[EDIM], Wcy[EDIM];
#pragma unroll
  for (int k = 0; k < EDIM; ++k) {
    float2 t = *(const float2*)(We + k * 1024 + col);
    Wcx[k] = t.x;
    Wcy[k] = t.y;
  }
  float2 av = *(const float2*)(att + col);
  float attAx = 0.6f * av.x, attBx = 0.4f * av.x;
  float attAy = 0.6f * av.y, attBy = 0.4f * av.y;
  u32 xru = *(const u32*)(xlr + (size_t)n * 2048 + 1024 + col);
  u32 xlu = *(const u32*)(xlr + (size_t)n * 2048 + col);
  float xrdx = bfu2f(xru & 0xffff), xrdy = bfu2f(xru >> 16);
  float xlsx = bfu2f(xlu & 0xffff), xlsy = bfu2f(xlu >> 16);

  auto escore2 = [&](int e, float xvx, float xvy) -> float {
    const float4* ea4 = (const float4*)(ea + (size_t)e * EDIM);
    float4 v0 = ea4[0], v1 = ea4[1], v2 = ea4[2], v3 = ea4[3];
    float ex = v0.x * Wcx[0], ey = v0.x * Wcy[0];
    ex = fmaf(v0.y, Wcx[1], ex); ey = fmaf(v0.y, Wcy[1], ey);
    ex = fmaf(v0.z, Wcx[2], ex); ey = fmaf(v0.z, Wcy[2], ey);
    ex = fmaf(v0.w, Wcx[3], ex); ey = fmaf(v0.w, Wcy[3], ey);
    ex = fmaf(v1.x, Wcx[4], ex); ey = fmaf(v1.x, Wcy[4], ey);
    ex = fmaf(v1.y, Wcx[5], ex); ey = fmaf(v1.y, Wcy[5], ey);
    ex = fmaf(v1.z, Wcx[6], ex); ey = fmaf(v1.z, Wcy[6], ey);
    ex = fmaf(v1.w, Wcx[7], ex); ey = fmaf(v1.w, Wcy[7], ey);
    ex = fmaf(v2.x, Wcx[8], ex); ey = fmaf(v2.x, Wcy[8], ey);
    ex = fmaf(v2.y, Wcx[9], ex); ey = fmaf(v2.y, Wcy[9], ey);
    ex = fmaf(v2.z, Wcx[10], ex); ey = fmaf(v2.z, Wcy[10], ey);
    ex = fmaf(v2.w, Wcx[11], ex); ey = fmaf(v2.w, Wcy[11], ey);
    ex = fmaf(v3.x, Wcx[12], ex); ey = fmaf(v3.x, Wcy[12], ey);
    ex = fmaf(v3.y, Wcx[13], ex); ey = fmaf(v3.y, Wcy[13], ey);
    ex = fmaf(v3.z, Wcx[14], ex); ey = fmaf(v3.z, Wcy[14], ey);
    ex = fmaf(v3.w, Wcx[15], ex); ey = fmaf(v3.w, Wcy[15], ey);
    float zx = xvx + xrdx + ex, zy = xvy + xrdy + ey;
    float p = fmaf(attAx, zx, attBx * fabsf(zx));
    p = fmaf(attAy, zy, p);
    p = fmaf(attBy, fabsf(zy), p);
    return p;
  };

  float accx = 0.f, accy = 0.f, denom = 0.f;
  int iend = r0 + ((r1 - r0) & ~3);
  int i = r0;
  if (i < iend) {
    int E[4], S[4];
    u32 X[4];
#pragma unroll
    for (int r = 0; r < 4; ++r) {
      E[r] = __builtin_amdgcn_readfirstlane(eid[i + r]);
      S[r] = __builtin_amdgcn_readfirstlane(srcp[i + r]);
    }
#pragma unroll
    for (int r = 0; r < 4; ++r) X[r] = *(const u32*)(xlr + (size_t)S[r] * 2048 + col);
    while (i < iend) {
      int inext = i + 4;
      int En[4], Sn[4];
      u32 Xn[4];
      bool more = inext < iend;
      if (more) {
#pragma unroll
        for (int r = 0; r < 4; ++r) {
          En[r] = __builtin_amdgcn_readfirstlane(eid[inext + r]);
          Sn[r] = __builtin_amdgcn_readfirstlane(srcp[inext + r]);
        }
#pragma unroll
        for (int r = 0; r < 4; ++r) Xn[r] = *(const u32*)(xlr + (size_t)Sn[r] * 2048 + col);
      }
      float x0x = bfu2f(X[0] & 0xffff), x0y = bfu2f(X[0] >> 16);
      float x1x = bfu2f(X[1] & 0xffff), x1y = bfu2f(X[1] >> 16);
      float x2x = bfu2f(X[2] & 0xffff), x2y = bfu2f(X[2] >> 16);
      float x3x = bfu2f(X[3] & 0xffff), x3y = bfu2f(X[3] >> 16);
      float p0 = escore2(E[0], x0x, x0y);
      float p1 = escore2(E[1], x1x, x1y);
      float p2 = escore2(E[2], x2x, x2y);
      float p3 = escore2(E[3], x3x, x3y);
      waveSum4(p0, p1, p2, p3);
      float w0 = __expf(p0), w1 = __expf(p1), w2 = __expf(p2), w3 = __expf(p3);
      accx = fmaf(w0, x0x, accx); accy = fmaf(w0, x0y, accy);
      accx = fmaf(w1, x1x, accx); accy = fmaf(w1, x1y, accy);
      accx = fmaf(w2, x2x, accx); accy = fmaf(w2, x2y, accy);
      accx = fmaf(w3, x3x, accx); accy = fmaf(w3, x3y, accy);
      denom += (w0 + w1) + (w2 + w3);
      if (more) {
#pragma unroll
        for (int r = 0; r < 4; ++r) {
          E[r] = En[r];
          S[r] = Sn[r];
          X[r] = Xn[r];
        }
      }
      i = inext;
    }
  }
  for (; i < r1; ++i) {
    int e = eid[i], s = srcp[i];
    u32 u0 = *(const u32*)(xlr + (size_t)s * 2048 + col);
    float xvx = bfu2f(u0 & 0xffff), xvy = bfu2f(u0 >> 16);
    float p = waveSum(escore2(e, xvx, xvy));
    float w = __expf(p);
    accx = fmaf(w, xvx, accx);
    accy = fmaf(w, xvy, accy);
    denom += w;
  }
  // self loop
  float eex = 0.f, eey = 0.f;
#pragma unroll
  for (int k = 0; k < EDIM; ++k) {
    float lv = la[n * EDIM + k];
    eex = fmaf(lv, Wcx[k], eex);
    eey = fmaf(lv, Wcy[k], eey);
  }
  float zx = xlsx + xrdx + eex, zy = xlsy + xrdy + eey;
  float ps = fmaf(attAx, zx, attBx * fabsf(zx));
  ps = fmaf(attAy, zy, ps);
  ps = fmaf(attBy, fabsf(zy), ps);
  float sc = waveSum(ps);
  float w = __expf(sc);
  accx = fmaf(w, xlsx, accx);
  accy = fmaf(w, xlsy, accy);
  denom += w;

  float inv = 1.f / denom;
  hsum[h][lane * 2] = accx * inv;
  hsum[h][lane * 2 + 1] = accy * inv;
  __syncthreads();
  if (tid < DD2) {
    float s = 0.f;
#pragma unroll
    for (int hh = 0; hh < H_HEADS; ++hh) s += hsum[hh][tid];
    out[(size_t)n * DD2 + tid] = f2bf(tanhf(s * 0.125f + bias[tid]));
  }
}

// ---------------- LSTM (single step, h0=c0=0) + FC ----------------
__global__ __launch_bounds__(128) void k_lstm(const float* __restrict__ gates,
                                              const float* __restrict__ b_ih,
                                              const float* __restrict__ b_hh,
                                              const float* __restrict__ fcW,
                                              const float* __restrict__ fcb,
                                              float* __restrict__ out) {
  int n = blockIdx.x;
  int j = threadIdx.x;
  __shared__ float gs[128];
  gs[j] = gates[(size_t)n * 128 + j] + b_ih[j] + b_hh[j];
  __syncthreads();
  if (j < 32) {
    float iv = gs[j], gv = gs[64 + j], ov = gs[96 + j];
    float c = (1.f / (1.f + __expf(-iv))) * tanhf(gv);
    float hd = (1.f / (1.f + __expf(-ov))) * tanhf(c);
    float p = hd * fcW[j];
#pragma unroll
    for (int off = 16; off > 0; off >>= 1) p += __shfl_down(p, off, 32);
    if (j == 0) out[n] = p + fcb[0];
  }
}

extern "C" void kernel_launch(void* const* d_in, const int* in_sizes, int n_in, void* d_out,
                              int out_size, void* d_ws, size_t ws_size, hipStream_t stream) {
  const float* x = (const float*)d_in[0];
  const int* ei = (const int*)d_in[1];
  const float* ea = (const float*)d_in[2];
  const float* Wl1 = (const float*)d_in[3];
  const float* Wr1 = (const float*)d_in[4];
  const float* We1 = (const float*)d_in[5];
  const float* att1 = (const float*)d_in[6];
  const float* b1 = (const float*)d_in[7];
  const float* Wl2 = (const float*)d_in[8];
  const float* Wr2 = (const float*)d_in[9];
  const float* We2 = (const float*)d_in[10];
  const float* att2 = (const float*)d_in[11];
  const float* b2 = (const float*)d_in[12];
  const float* W_ih = (const float*)d_in[13];
  const float* b_ih = (const float*)d_in[15];
  const float* b_hh = (const float*)d_in[16];
  const float* fcW = (const float*)d_in[17];
  const float* fcb = (const float*)d_in[18];
  float* out = (float*)d_out;
  const int* srcA = ei;
  const int* dstA = ei + N_EDGES;

  char* ws = (char*)d_ws;
  // big aliased regions:
  //   [0, 102.4M)        xlr1 [50000x1024] bf16; later xlr2 [50000x2048] spans [0, 204.8M)
  //   [102.4M, 144.1M)   xbf  [M_PAD x 416] bf16 (dead before xlr2 written)
  //   [204.8M, 256.05M)  h1   [M_PAD x 512] bf16; later h2 [M_PAD x 128] + gates [M_PAD x 128] f32
  const size_t OFF_XBF = (size_t)N_NODES * 1024 * 2;            // 102,400,000
  const size_t OFF_H1 = (size_t)N_NODES * 2048 * 2;             // 204,800,000
  const size_t OFF_GATES = OFF_H1 + (size_t)M_PAD * 128 * 2;    // 217,612,288
  size_t off = OFF_H1 + (size_t)M_PAD * 512 * 2;                // 256,049,152
  auto take = [&](size_t bytes) -> char* {
    off = (off + 255) & ~(size_t)255;
    char* p = ws + off;
    off += bytes;
    return p;
  };
  u16* W1T = (u16*)take((size_t)1024 * K1_PAD * 2);  // [Wl1T ; Wr1T]
  u16* W2T = (u16*)take((size_t)2048 * 512 * 2);     // [Wl2T ; Wr2T]
  u16* WihB = (u16*)take((size_t)128 * 128 * 2);
  int* deg = (int*)take((size_t)N_NODES * 4);
  int* cursor = (int*)take((size_t)N_NODES * 4);
  int* row_start = (int*)take((size_t)(N_NODES + 1) * 4);
  int* eid = (int*)take((size_t)N_EDGES * 4);
  int* srcp = (int*)take((size_t)N_EDGES * 4);
  float* la = (float*)take((size_t)N_NODES * EDIM * 4);

  if (off > ws_size) {
    k_zero<<<(out_size + 255) / 256, 256, 0, stream>>>(out, out_size);
    return;
  }

  u16* xlr1 = (u16*)ws;
  u16* xbf = (u16*)(ws + OFF_XBF);
  u16* xlr2 = (u16*)ws;
  u16* h1 = (u16*)(ws + OFF_H1);
  u16* h2 = (u16*)(ws + OFF_H1);
  float* gates = (float*)(ws + OFF_GATES);

  hipMemsetAsync(deg, 0, (size_t)N_NODES * 4, stream);
  hipMemsetAsync(cursor, 0, (size_t)N_NODES * 4, stream);
  k_hist<<<(N_EDGES + 255) / 256, 256, 0, stream>>>(dstA, deg);
  k_scan<<<1, 1024, 0, stream>>>(deg, row_start);
  k_scatter<<<(N_EDGES + 255) / 256, 256, 0, stream>>>(dstA, srcA, row_start, cursor, eid, srcp);
  k_la<<<(N_NODES + 15) / 16, 256, 0, stream>>>(ea, eid, row_start, la);

  {
    long tot = (long)M_PAD * K1_PAD;
    k_cvt_x<<<(unsigned)((tot + 255) / 256), 256, 0, stream>>>(x, xbf);
    k_cvt_wT<<<(512 * K1_PAD + 255) / 256, 256, 0, stream>>>(Wl1, W1T, F_INDIM, 512, K1_PAD);
    k_cvt_wT<<<(512 * K1_PAD + 255) / 256, 256, 0, stream>>>(Wr1, W1T + (size_t)512 * K1_PAD,
                                                             F_INDIM, 512, K1_PAD);
    k_cvt_wT<<<(1024 * 512 + 255) / 256, 256, 0, stream>>>(Wl2, W2T, 512, 1024, 512);
    k_cvt_wT<<<(1024 * 512 + 255) / 256, 256, 0, stream>>>(Wr2, W2T + (size_t)1024 * 512, 512,
                                                           1024, 512);
    k_cvt<<<(128 * 128 + 255) / 256, 256, 0, stream>>>(W_ih, WihB, 128 * 128);
  }

  const int MB = M_PAD / 128;  // 391
  // layer 1 fused GEMM: [50000 x 416] @ [416 x 1024] -> xlr1
  gemm_mfma<false><<<dim3(1024 / 128, MB), 256, 0, stream>>>(xbf, W1T, xlr1, N_NODES, 1024,
                                                             K1_PAD, K1_PAD, K1_PAD);
  k_gat1<<<N_NODES, 512, 0, stream>>>(xlr1, ea, We1, att1, b1, srcp, eid, row_start, la, h1);

  // layer 2 fused GEMM: [50000 x 512] @ [512 x 2048] -> xlr2
  gemm_mfma<false><<<dim3(2048 / 128, MB), 256, 0, stream>>>(h1, W2T, xlr2, N_NODES, 2048, 512,
                                                             512, 512);
  k_gat2<<<N_NODES, 512, 0, stream>>>(xlr2, ea, We2, att2, b2, srcp, eid, row_start, la, h2);

  // gates GEMM: [50000 x 128] @ [128 x 128]
  gemm_mfma<true><<<dim3(1, MB), 256, 0, stream>>>(h2, WihB, gates, N_NODES, 128, 128, 128, 128);
  k_lstm<<<N_NODES, 128, 0, stream>>>(gates, b_ih, b_hh, fcW, fcb, out);
}

// Round 6
// 1534.708 us; speedup vs baseline: 1.0967x; 1.0967x over previous
//
#include <hip/hip_runtime.h>

#define N_NODES 50000
#define N_EDGES 500000
#define F_INDIM 388
#define H_HEADS 8
#define DD1 64
#define DD2 128
#define EDIM 16
#define HIDN 32

#define M_PAD 50048   // 391*128
#define K1_PAD 416    // 388 padded to mult of 32

typedef unsigned short u16;
typedef unsigned int u32;
typedef __attribute__((ext_vector_type(8))) short bf16x8;
typedef __attribute__((ext_vector_type(4))) float f32x4;

static __device__ __forceinline__ float bfu2f(u32 lo16) {
  union { u32 u; float f; } c;
  c.u = lo16 << 16;
  return c.f;
}
static __device__ __forceinline__ u16 f2bf(float f) {
  union { float f; u32 u; } c;
  c.f = f;
  u32 u = c.u + 0x7fffu + ((c.u >> 16) & 1u);
  return (u16)(u >> 16);
}

static __device__ __forceinline__ float waveSum(float v) {
#pragma unroll
  for (int off = 32; off > 0; off >>= 1) v += __shfl_xor(v, off, 64);
  return v;
}
static __device__ __forceinline__ void waveSum4(float& a, float& b, float& c, float& d) {
#pragma unroll
  for (int off = 32; off > 0; off >>= 1) {
    a += __shfl_xor(a, off, 64);
    b += __shfl_xor(b, off, 64);
    c += __shfl_xor(c, off, 64);
    d += __shfl_xor(d, off, 64);
  }
}

static __device__ __forceinline__ void gl_lds16(const void* g, void* l) {
  __builtin_amdgcn_global_load_lds((const __attribute__((address_space(1))) u32*)g,
                                   (__attribute__((address_space(3))) u32*)l, 16, 0, 0);
}

__global__ void k_zero(float* __restrict__ out, int n) {
  int i = blockIdx.x * blockDim.x + threadIdx.x;
  if (i < n) out[i] = 0.f;
}

// ---------------- CSR build ----------------
__global__ void k_hist(const int* __restrict__ dst, int* __restrict__ deg) {
  int e = blockIdx.x * blockDim.x + threadIdx.x;
  if (e < N_EDGES) atomicAdd(&deg[dst[e]], 1);
}

__global__ __launch_bounds__(1024) void k_scan(const int* __restrict__ deg,
                                               int* __restrict__ row_start) {
  __shared__ int wsum[16];
  __shared__ int carry_s;
  int tid = threadIdx.x;
  int lane = tid & 63, wv = tid >> 6;
  if (tid == 0) carry_s = 0;
  __syncthreads();
  for (int base = 0; base < N_NODES; base += 1024) {
    int i = base + tid;
    int v = (i < N_NODES) ? deg[i] : 0;
    int inc = v;
#pragma unroll
    for (int off = 1; off < 64; off <<= 1) {
      int t = __shfl_up(inc, off, 64);
      if (lane >= off) inc += t;
    }
    if (lane == 63) wsum[wv] = inc;
    __syncthreads();
    if (wv == 0 && lane < 16) {
      int s = wsum[lane];
#pragma unroll
      for (int off = 1; off < 16; off <<= 1) {
        int t = __shfl_up(s, off, 64);
        if (lane >= off) s += t;
      }
      wsum[lane] = s;
    }
    __syncthreads();
    int add = (wv > 0) ? wsum[wv - 1] : 0;
    int ex = carry_s + add + inc - v;
    if (i < N_NODES) row_start[i] = ex;
    __syncthreads();
    if (tid == 0) carry_s += wsum[15];
    __syncthreads();
  }
  if (threadIdx.x == 0) row_start[N_NODES] = carry_s;
}

__global__ void k_scatter(const int* __restrict__ dst, const int* __restrict__ src,
                          const int* __restrict__ row_start, int* __restrict__ cursor,
                          int* __restrict__ eid, int* __restrict__ srcp) {
  int e = blockIdx.x * blockDim.x + threadIdx.x;
  if (e < N_EDGES) {
    int d = dst[e];
    int pos = row_start[d] + atomicAdd(&cursor[d], 1);
    eid[pos] = e;
    srcp[pos] = src[e];
  }
}

// ---------------- loop_attr: la[n][16] = mean of ea rows over in-edges ----------------
__global__ __launch_bounds__(256) void k_la(const float* __restrict__ ea,
                                            const int* __restrict__ eid,
                                            const int* __restrict__ row_start,
                                            float* __restrict__ la) {
  int node = blockIdx.x * 16 + (threadIdx.x >> 4);
  int k = threadIdx.x & 15;
  if (node >= N_NODES) return;
  int r0 = row_start[node], r1 = row_start[node + 1];
  float s = 0.f;
  for (int i = r0; i < r1; ++i) s += ea[(size_t)eid[i] * EDIM + k];
  la[node * EDIM + k] = s / (float)max(r1 - r0, 1);
}

// ---------------- conversions ----------------
__global__ void k_cvt_x(const float* __restrict__ x, u16* __restrict__ xb) {
  long t = (long)blockIdx.x * 256 + threadIdx.x;
  if (t >= (long)M_PAD * K1_PAD) return;
  int row = (int)(t / K1_PAD);
  int col = (int)(t % K1_PAD);
  float v = (row < N_NODES && col < F_INDIM) ? x[(size_t)row * F_INDIM + col] : 0.f;
  xb[t] = f2bf(v);
}

// W fp32 [K][N] -> WT bf16 [N][Kp], zero pad k>=K
__global__ void k_cvt_wT(const float* __restrict__ W, u16* __restrict__ WT, int K, int N, int Kp) {
  int t = blockIdx.x * 256 + threadIdx.x;
  if (t >= N * Kp) return;
  int n = t / Kp, k = t % Kp;
  WT[t] = f2bf(k < K ? W[(size_t)k * N + n] : 0.f);
}

__global__ void k_cvt(const float* __restrict__ W, u16* __restrict__ O, int n) {
  int t = blockIdx.x * 256 + threadIdx.x;
  if (t < n) O[t] = f2bf(W[t]);
}

// ---------------- MFMA bf16 GEMM: C[M,Nd] = A[M,K] @ BT[Nd,K]^T ----------------
template <bool CF32>
__global__ __launch_bounds__(256) void gemm_mfma(const u16* __restrict__ A,
                                                 const u16* __restrict__ BT,
                                                 void* __restrict__ Cv, int M, int Nd, int K,
                                                 int lda, int ldb) {
  __shared__ u16 As[128 * 32];
  __shared__ u16 Bs[128 * 32];
  int tid = threadIdx.x;
  int lane = tid & 63;
  int wv = tid >> 6;
  int m_base = blockIdx.y * 128;
  int n_base = blockIdx.x * 128;
  int wrow = (wv >> 1) * 64;
  int wcol = (wv & 1) * 64;
  f32x4 acc[4][4];
#pragma unroll
  for (int i = 0; i < 4; ++i)
#pragma unroll
    for (int j = 0; j < 4; ++j)
#pragma unroll
      for (int r = 0; r < 4; ++r) acc[i][j][r] = 0.f;

  for (int k0 = 0; k0 < K; k0 += 32) {
    __syncthreads();
#pragma unroll
    for (int it = 0; it < 2; ++it) {
      int t = it * 256 + tid;
      int row = t >> 2;
      int kc = (t & 3) * 8;
      gl_lds16(A + (size_t)(m_base + row) * lda + k0 + kc, As + (size_t)(it * 256 + wv * 64) * 8);
      gl_lds16(BT + (size_t)(n_base + row) * ldb + k0 + kc, Bs + (size_t)(it * 256 + wv * 64) * 8);
    }
    __syncthreads();
    bf16x8 af[4], bfr[4];
#pragma unroll
    for (int i = 0; i < 4; ++i) {
      int r = wrow + i * 16 + (lane & 15);
      af[i] = *(const bf16x8*)(As + r * 32 + (lane >> 4) * 8);
    }
#pragma unroll
    for (int j = 0; j < 4; ++j) {
      int r = wcol + j * 16 + (lane & 15);
      bfr[j] = *(const bf16x8*)(Bs + r * 32 + (lane >> 4) * 8);
    }
#pragma unroll
    for (int i = 0; i < 4; ++i)
#pragma unroll
      for (int j = 0; j < 4; ++j)
        acc[i][j] = __builtin_amdgcn_mfma_f32_16x16x32_bf16(af[i], bfr[j], acc[i][j], 0, 0, 0);
  }
#pragma unroll
  for (int i = 0; i < 4; ++i) {
    int grow_base = m_base + wrow + i * 16 + (lane >> 4) * 4;
#pragma unroll
    for (int j = 0; j < 4; ++j) {
      int gcol = n_base + wcol + j * 16 + (lane & 15);
#pragma unroll
      for (int r = 0; r < 4; ++r) {
        int grow = grow_base + r;
        if (grow < M) {
          float v = acc[i][j][r];
          if (CF32)
            ((float*)Cv)[(size_t)grow * Nd + gcol] = v;
          else
            ((u16*)Cv)[(size_t)grow * Nd + gcol] = f2bf(v);
        }
      }
    }
  }
}

// ---------------- GAT layer 1 (D=64, concat) ----------------
// xlr: [n][xl(512)|xr(512)] bf16. lrelu folded: p = 0.6a*z + 0.4a*|z|. No LDS/barriers.
__global__ __launch_bounds__(512) void k_gat1(
    const u16* __restrict__ xlr, const float* __restrict__ ea, const float* __restrict__ We,
    const float* __restrict__ att, const float* __restrict__ bias, const int* __restrict__ srcp,
    const int* __restrict__ eid, const int* __restrict__ row_start, const float* __restrict__ la,
    u16* __restrict__ out) {
  int n = blockIdx.x;
  int col = threadIdx.x;  // 0..511, wave == head
  int r0 = row_start[n], r1 = row_start[n + 1];
  float Wc[EDIM];
#pragma unroll
  for (int k = 0; k < EDIM; ++k) Wc[k] = We[k * 512 + col];
  float a = att[col];
  float attA = 0.6f * a, attB = 0.4f * a;
  float xrd = bfu2f(xlr[(size_t)n * 1024 + 512 + col]);
  float xlself = bfu2f(xlr[(size_t)n * 1024 + col]);

  auto escore = [&](int e, float xv) -> float {
    const float4* ea4 = (const float4*)(ea + (size_t)e * EDIM);
    float4 v0 = ea4[0], v1 = ea4[1], v2 = ea4[2], v3 = ea4[3];
    float t = v0.x * Wc[0];
    t = fmaf(v0.y, Wc[1], t);
    t = fmaf(v0.z, Wc[2], t);
    t = fmaf(v0.w, Wc[3], t);
    t = fmaf(v1.x, Wc[4], t);
    t = fmaf(v1.y, Wc[5], t);
    t = fmaf(v1.z, Wc[6], t);
    t = fmaf(v1.w, Wc[7], t);
    t = fmaf(v2.x, Wc[8], t);
    t = fmaf(v2.y, Wc[9], t);
    t = fmaf(v2.z, Wc[10], t);
    t = fmaf(v2.w, Wc[11], t);
    t = fmaf(v3.x, Wc[12], t);
    t = fmaf(v3.y, Wc[13], t);
    t = fmaf(v3.z, Wc[14], t);
    t = fmaf(v3.w, Wc[15], t);
    float z = xv + xrd + t;
    return fmaf(attA, z, attB * fabsf(z));
  };

  float acc = 0.f, denom = 0.f;
  int i = r0;
  for (; i + 4 <= r1; i += 4) {
    int e0 = eid[i], e1 = eid[i + 1], e2 = eid[i + 2], e3 = eid[i + 3];
    int s0 = srcp[i], s1 = srcp[i + 1], s2 = srcp[i + 2], s3 = srcp[i + 3];
    float x0 = bfu2f(xlr[(size_t)s0 * 1024 + col]);
    float x1 = bfu2f(xlr[(size_t)s1 * 1024 + col]);
    float x2 = bfu2f(xlr[(size_t)s2 * 1024 + col]);
    float x3 = bfu2f(xlr[(size_t)s3 * 1024 + col]);
    float p0 = escore(e0, x0);
    float p1 = escore(e1, x1);
    float p2 = escore(e2, x2);
    float p3 = escore(e3, x3);
    waveSum4(p0, p1, p2, p3);
    float w0 = __expf(p0), w1 = __expf(p1), w2 = __expf(p2), w3 = __expf(p3);
    acc = fmaf(w0, x0, acc);
    acc = fmaf(w1, x1, acc);
    acc = fmaf(w2, x2, acc);
    acc = fmaf(w3, x3, acc);
    denom += (w0 + w1) + (w2 + w3);
  }
  for (; i < r1; ++i) {
    int e = eid[i], s = srcp[i];
    float xv = bfu2f(xlr[(size_t)s * 1024 + col]);
    float p = waveSum(escore(e, xv));
    float w = __expf(p);
    acc = fmaf(w, xv, acc);
    denom += w;
  }
  // self loop via precomputed la
  float ee = 0.f;
#pragma unroll
  for (int k = 0; k < EDIM; ++k) ee = fmaf(la[n * EDIM + k], Wc[k], ee);
  float z = xlself + xrd + ee;
  float sc = waveSum(fmaf(attA, z, attB * fabsf(z)));
  float w = __expf(sc);
  acc = fmaf(w, xlself, acc);
  denom += w;
  out[(size_t)n * 512 + col] = f2bf(tanhf(acc / denom + bias[col]));
}

// ---------------- GAT layer 2 (D=128, mean heads) ----------------
// xlr: [n][xl(1024)|xr(1024)] bf16.
__global__ __launch_bounds__(512) void k_gat2(
    const u16* __restrict__ xlr, const float* __restrict__ ea, const float* __restrict__ We,
    const float* __restrict__ att, const float* __restrict__ bias, const int* __restrict__ srcp,
    const int* __restrict__ eid, const int* __restrict__ row_start, const float* __restrict__ la,
    u16* __restrict__ out) {
  int n = blockIdx.x;
  int tid = threadIdx.x;
  int lane = tid & 63;
  int h = tid >> 6;
  __shared__ float hsum[H_HEADS][DD2];
  int r0 = row_start[n], r1 = row_start[n + 1];
  int col = h * DD2 + lane * 2;
  float Wcx[EDIM], Wcy[EDIM];
#pragma unroll
  for (int k = 0; k < EDIM; ++k) {
    float2 t = *(const float2*)(We + k * 1024 + col);
    Wcx[k] = t.x;
    Wcy[k] = t.y;
  }
  float2 av = *(const float2*)(att + col);
  float attAx = 0.6f * av.x, attBx = 0.4f * av.x;
  float attAy = 0.6f * av.y, attBy = 0.4f * av.y;
  u32 xru = *(const u32*)(xlr + (size_t)n * 2048 + 1024 + col);
  u32 xlu = *(const u32*)(xlr + (size_t)n * 2048 + col);
  float xrdx = bfu2f(xru & 0xffff), xrdy = bfu2f(xru >> 16);
  float xlsx = bfu2f(xlu & 0xffff), xlsy = bfu2f(xlu >> 16);

  auto escore2 = [&](int e, float xvx, float xvy) -> float {
    const float4* ea4 = (const float4*)(ea + (size_t)e * EDIM);
    float4 v0 = ea4[0], v1 = ea4[1], v2 = ea4[2], v3 = ea4[3];
    float ex = v0.x * Wcx[0], ey = v0.x * Wcy[0];
    ex = fmaf(v0.y, Wcx[1], ex); ey = fmaf(v0.y, Wcy[1], ey);
    ex = fmaf(v0.z, Wcx[2], ex); ey = fmaf(v0.z, Wcy[2], ey);
    ex = fmaf(v0.w, Wcx[3], ex); ey = fmaf(v0.w, Wcy[3], ey);
    ex = fmaf(v1.x, Wcx[4], ex); ey = fmaf(v1.x, Wcy[4], ey);
    ex = fmaf(v1.y, Wcx[5], ex); ey = fmaf(v1.y, Wcy[5], ey);
    ex = fmaf(v1.z, Wcx[6], ex); ey = fmaf(v1.z, Wcy[6], ey);
    ex = fmaf(v1.w, Wcx[7], ex); ey = fmaf(v1.w, Wcy[7], ey);
    ex = fmaf(v2.x, Wcx[8], ex); ey = fmaf(v2.x, Wcy[8], ey);
    ex = fmaf(v2.y, Wcx[9], ex); ey = fmaf(v2.y, Wcy[9], ey);
    ex = fmaf(v2.z, Wcx[10], ex); ey = fmaf(v2.z, Wcy[10], ey);
    ex = fmaf(v2.w, Wcx[11], ex); ey = fmaf(v2.w, Wcy[11], ey);
    ex = fmaf(v3.x, Wcx[12], ex); ey = fmaf(v3.x, Wcy[12], ey);
    ex = fmaf(v3.y, Wcx[13], ex); ey = fmaf(v3.y, Wcy[13], ey);
    ex = fmaf(v3.z, Wcx[14], ex); ey = fmaf(v3.z, Wcy[14], ey);
    ex = fmaf(v3.w, Wcx[15], ex); ey = fmaf(v3.w, Wcy[15], ey);
    float zx = xvx + xrdx + ex, zy = xvy + xrdy + ey;
    float p = fmaf(attAx, zx, attBx * fabsf(zx));
    p = fmaf(attAy, zy, p);
    p = fmaf(attBy, fabsf(zy), p);
    return p;
  };

  float accx = 0.f, accy = 0.f, denom = 0.f;
  int i = r0;
  for (; i + 4 <= r1; i += 4) {
    int e0 = eid[i], e1 = eid[i + 1], e2 = eid[i + 2], e3 = eid[i + 3];
    int s0 = srcp[i], s1 = srcp[i + 1], s2 = srcp[i + 2], s3 = srcp[i + 3];
    u32 u0 = *(const u32*)(xlr + (size_t)s0 * 2048 + col);
    u32 u1 = *(const u32*)(xlr + (size_t)s1 * 2048 + col);
    u32 u2 = *(const u32*)(xlr + (size_t)s2 * 2048 + col);
    u32 u3 = *(const u32*)(xlr + (size_t)s3 * 2048 + col);
    float x0x = bfu2f(u0 & 0xffff), x0y = bfu2f(u0 >> 16);
    float x1x = bfu2f(u1 & 0xffff), x1y = bfu2f(u1 >> 16);
    float x2x = bfu2f(u2 & 0xffff), x2y = bfu2f(u2 >> 16);
    float x3x = bfu2f(u3 & 0xffff), x3y = bfu2f(u3 >> 16);
    float p0 = escore2(e0, x0x, x0y);
    float p1 = escore2(e1, x1x, x1y);
    float p2 = escore2(e2, x2x, x2y);
    float p3 = escore2(e3, x3x, x3y);
    waveSum4(p0, p1, p2, p3);
    float w0 = __expf(p0), w1 = __expf(p1), w2 = __expf(p2), w3 = __expf(p3);
    accx = fmaf(w0, x0x, accx); accy = fmaf(w0, x0y, accy);
    accx = fmaf(w1, x1x, accx); accy = fmaf(w1, x1y, accy);
    accx = fmaf(w2, x2x, accx); accy = fmaf(w2, x2y, accy);
    accx = fmaf(w3, x3x, accx); accy = fmaf(w3, x3y, accy);
    denom += (w0 + w1) + (w2 + w3);
  }
  for (; i < r1; ++i) {
    int e = eid[i], s = srcp[i];
    u32 u0 = *(const u32*)(xlr + (size_t)s * 2048 + col);
    float xvx = bfu2f(u0 & 0xffff), xvy = bfu2f(u0 >> 16);
    float p = waveSum(escore2(e, xvx, xvy));
    float w = __expf(p);
    accx = fmaf(w, xvx, accx);
    accy = fmaf(w, xvy, accy);
    denom += w;
  }
  // self loop
  float eex = 0.f, eey = 0.f;
#pragma unroll
  for (int k = 0; k < EDIM; ++k) {
    float lv = la[n * EDIM + k];
    eex = fmaf(lv, Wcx[k], eex);
    eey = fmaf(lv, Wcy[k], eey);
  }
  float zx = xlsx + xrdx + eex, zy = xlsy + xrdy + eey;
  float ps = fmaf(attAx, zx, attBx * fabsf(zx));
  ps = fmaf(attAy, zy, ps);
  ps = fmaf(attBy, fabsf(zy), ps);
  float sc = waveSum(ps);
  float w = __expf(sc);
  accx = fmaf(w, xlsx, accx);
  accy = fmaf(w, xlsy, accy);
  denom += w;

  float inv = 1.f / denom;
  hsum[h][lane * 2] = accx * inv;
  hsum[h][lane * 2 + 1] = accy * inv;
  __syncthreads();
  if (tid < DD2) {
    float s = 0.f;
#pragma unroll
    for (int hh = 0; hh < H_HEADS; ++hh) s += hsum[hh][tid];
    out[(size_t)n * DD2 + tid] = f2bf(tanhf(s * 0.125f + bias[tid]));
  }
}

// ---------------- LSTM (single step, h0=c0=0) + FC ----------------
__global__ __launch_bounds__(128) void k_lstm(const float* __restrict__ gates,
                                              const float* __restrict__ b_ih,
                                              const float* __restrict__ b_hh,
                                              const float* __restrict__ fcW,
                                              const float* __restrict__ fcb,
                                              float* __restrict__ out) {
  int n = blockIdx.x;
  int j = threadIdx.x;
  __shared__ float gs[128];
  gs[j] = gates[(size_t)n * 128 + j] + b_ih[j] + b_hh[j];
  __syncthreads();
  if (j < 32) {
    float iv = gs[j], gv = gs[64 + j], ov = gs[96 + j];
    float c = (1.f / (1.f + __expf(-iv))) * tanhf(gv);
    float hd = (1.f / (1.f + __expf(-ov))) * tanhf(c);
    float p = hd * fcW[j];
#pragma unroll
    for (int off = 16; off > 0; off >>= 1) p += __shfl_down(p, off, 32);
    if (j == 0) out[n] = p + fcb[0];
  }
}

extern "C" void kernel_launch(void* const* d_in, const int* in_sizes, int n_in, void* d_out,
                              int out_size, void* d_ws, size_t ws_size, hipStream_t stream) {
  const float* x = (const float*)d_in[0];
  const int* ei = (const int*)d_in[1];
  const float* ea = (const float*)d_in[2];
  const float* Wl1 = (const float*)d_in[3];
  const float* Wr1 = (const float*)d_in[4];
  const float* We1 = (const float*)d_in[5];
  const float* att1 = (const float*)d_in[6];
  const float* b1 = (const float*)d_in[7];
  const float* Wl2 = (const float*)d_in[8];
  const float* Wr2 = (const float*)d_in[9];
  const float* We2 = (const float*)d_in[10];
  const float* att2 = (const float*)d_in[11];
  const float* b2 = (const float*)d_in[12];
  const float* W_ih = (const float*)d_in[13];
  const float* b_ih = (const float*)d_in[15];
  const float* b_hh = (const float*)d_in[16];
  const float* fcW = (const float*)d_in[17];
  const float* fcb = (const float*)d_in[18];
  float* out = (float*)d_out;
  const int* srcA = ei;
  const int* dstA = ei + N_EDGES;

  char* ws = (char*)d_ws;
  const size_t OFF_XBF = (size_t)N_NODES * 1024 * 2;            // 102,400,000
  const size_t OFF_H1 = (size_t)N_NODES * 2048 * 2;             // 204,800,000
  const size_t OFF_GATES = OFF_H1 + (size_t)M_PAD * 128 * 2;    // 217,612,288
  size_t off = OFF_H1 + (size_t)M_PAD * 512 * 2;                // 256,049,152
  auto take = [&](size_t bytes) -> char* {
    off = (off + 255) & ~(size_t)255;
    char* p = ws + off;
    off += bytes;
    return p;
  };
  u16* W1T = (u16*)take((size_t)1024 * K1_PAD * 2);  // [Wl1T ; Wr1T]
  u16* W2T = (u16*)take((size_t)2048 * 512 * 2);     // [Wl2T ; Wr2T]
  u16* WihB = (u16*)take((size_t)128 * 128 * 2);
  int* deg = (int*)take((size_t)N_NODES * 4);
  int* cursor = (int*)take((size_t)N_NODES * 4);
  int* row_start = (int*)take((size_t)(N_NODES + 1) * 4);
  int* eid = (int*)take((size_t)N_EDGES * 4);
  int* srcp = (int*)take((size_t)N_EDGES * 4);
  float* la = (float*)take((size_t)N_NODES * EDIM * 4);

  if (off > ws_size) {
    k_zero<<<(out_size + 255) / 256, 256, 0, stream>>>(out, out_size);
    return;
  }

  u16* xlr1 = (u16*)ws;
  u16* xbf = (u16*)(ws + OFF_XBF);
  u16* xlr2 = (u16*)ws;
  u16* h1 = (u16*)(ws + OFF_H1);
  u16* h2 = (u16*)(ws + OFF_H1);
  float* gates = (float*)(ws + OFF_GATES);

  hipMemsetAsync(deg, 0, (size_t)N_NODES * 4, stream);
  hipMemsetAsync(cursor, 0, (size_t)N_NODES * 4, stream);
  k_hist<<<(N_EDGES + 255) / 256, 256, 0, stream>>>(dstA, deg);
  k_scan<<<1, 1024, 0, stream>>>(deg, row_start);
  k_scatter<<<(N_EDGES + 255) / 256, 256, 0, stream>>>(dstA, srcA, row_start, cursor, eid, srcp);
  k_la<<<(N_NODES + 15) / 16, 256, 0, stream>>>(ea, eid, row_start, la);

  {
    long tot = (long)M_PAD * K1_PAD;
    k_cvt_x<<<(unsigned)((tot + 255) / 256), 256, 0, stream>>>(x, xbf);
    k_cvt_wT<<<(512 * K1_PAD + 255) / 256, 256, 0, stream>>>(Wl1, W1T, F_INDIM, 512, K1_PAD);
    k_cvt_wT<<<(512 * K1_PAD + 255) / 256, 256, 0, stream>>>(Wr1, W1T + (size_t)512 * K1_PAD,
                                                             F_INDIM, 512, K1_PAD);
    k_cvt_wT<<<(1024 * 512 + 255) / 256, 256, 0, stream>>>(Wl2, W2T, 512, 1024, 512);
    k_cvt_wT<<<(1024 * 512 + 255) / 256, 256, 0, stream>>>(Wr2, W2T + (size_t)1024 * 512, 512,
                                                           1024, 512);
    k_cvt<<<(128 * 128 + 255) / 256, 256, 0, stream>>>(W_ih, WihB, 128 * 128);
  }

  const int MB = M_PAD / 128;  // 391
  // layer 1 fused GEMM: [50000 x 416] @ [416 x 1024] -> xlr1
  gemm_mfma<false><<<dim3(1024 / 128, MB), 256, 0, stream>>>(xbf, W1T, xlr1, N_NODES, 1024,
                                                             K1_PAD, K1_PAD, K1_PAD);
  k_gat1<<<N_NODES, 512, 0, stream>>>(xlr1, ea, We1, att1, b1, srcp, eid, row_start, la, h1);

  // layer 2 fused GEMM: [50000 x 512] @ [512 x 2048] -> xlr2
  gemm_mfma<false><<<dim3(2048 / 128, MB), 256, 0, stream>>>(h1, W2T, xlr2, N_NODES, 2048, 512,
                                                             512, 512);
  k_gat2<<<N_NODES, 512, 0, stream>>>(xlr2, ea, We2, att2, b2, srcp, eid, row_start, la, h2);

  // gates GEMM: [50000 x 128] @ [128 x 128]
  gemm_mfma<true><<<dim3(1, MB), 256, 0, stream>>>(h2, WihB, gates, N_NODES, 128, 128, 128, 128);
  k_lstm<<<N_NODES, 128, 0, stream>>>(gates, b_ih, b_hh, fcW, fcb, out);
}

// Round 7
// 1369.810 us; speedup vs baseline: 1.2287x; 1.1204x over previous
//
#include <hip/hip_runtime.h>

#define N_NODES 50000
#define N_EDGES 500000
#define F_INDIM 388
#define H_HEADS 8
#define DD1 64
#define DD2 128
#define EDIM 16
#define HIDN 32

#define M_PAD 50048   // 391*128
#define K1_PAD 416    // 388 padded to mult of 32

typedef unsigned short u16;
typedef unsigned int u32;
typedef __attribute__((ext_vector_type(8))) short bf16x8;
typedef __attribute__((ext_vector_type(4))) float f32x4;
typedef __attribute__((ext_vector_type(2))) float f32x2;

static __device__ __forceinline__ u16 f2bf(float f) {
  union { float f; u32 u; } c;
  c.f = f;
  u32 u = c.u + 0x7fffu + ((c.u >> 16) & 1u);
  return (u16)(u >> 16);
}
// unpack a u32 holding two bf16 (lo, hi) into float2 — 2 VALU ops
static __device__ __forceinline__ f32x2 bf2f2(u32 u) {
  union { u32 u; float f; } lo, hi;
  lo.u = u << 16;
  hi.u = u & 0xffff0000u;
  f32x2 r;
  r.x = lo.f;
  r.y = hi.f;
  return r;
}
static __device__ __forceinline__ f32x2 abs2(f32x2 v) {
  f32x2 r;
  r.x = fabsf(v.x);
  r.y = fabsf(v.y);
  return r;
}

// sum within each 32-lane half (head-local), 4 values interleaved
static __device__ __forceinline__ void halfSum4(float& a, float& b, float& c, float& d) {
#pragma unroll
  for (int off = 1; off < 32; off <<= 1) {
    a += __shfl_xor(a, off, 64);
    b += __shfl_xor(b, off, 64);
    c += __shfl_xor(c, off, 64);
    d += __shfl_xor(d, off, 64);
  }
}
static __device__ __forceinline__ float halfSum(float v) {
#pragma unroll
  for (int off = 1; off < 32; off <<= 1) v += __shfl_xor(v, off, 64);
  return v;
}

static __device__ __forceinline__ void gl_lds16(const void* g, void* l) {
  __builtin_amdgcn_global_load_lds((const __attribute__((address_space(1))) u32*)g,
                                   (__attribute__((address_space(3))) u32*)l, 16, 0, 0);
}

__global__ void k_zero(float* __restrict__ out, int n) {
  int i = blockIdx.x * blockDim.x + threadIdx.x;
  if (i < n) out[i] = 0.f;
}

// ---------------- CSR build ----------------
__global__ void k_hist(const int* __restrict__ dst, int* __restrict__ deg) {
  int e = blockIdx.x * blockDim.x + threadIdx.x;
  if (e < N_EDGES) atomicAdd(&deg[dst[e]], 1);
}

__global__ __launch_bounds__(1024) void k_scan(const int* __restrict__ deg,
                                               int* __restrict__ row_start) {
  __shared__ int wsum[16];
  __shared__ int carry_s;
  int tid = threadIdx.x;
  int lane = tid & 63, wv = tid >> 6;
  if (tid == 0) carry_s = 0;
  __syncthreads();
  for (int base = 0; base < N_NODES; base += 1024) {
    int i = base + tid;
    int v = (i < N_NODES) ? deg[i] : 0;
    int inc = v;
#pragma unroll
    for (int off = 1; off < 64; off <<= 1) {
      int t = __shfl_up(inc, off, 64);
      if (lane >= off) inc += t;
    }
    if (lane == 63) wsum[wv] = inc;
    __syncthreads();
    if (wv == 0 && lane < 16) {
      int s = wsum[lane];
#pragma unroll
      for (int off = 1; off < 16; off <<= 1) {
        int t = __shfl_up(s, off, 64);
        if (lane >= off) s += t;
      }
      wsum[lane] = s;
    }
    __syncthreads();
    int add = (wv > 0) ? wsum[wv - 1] : 0;
    int ex = carry_s + add + inc - v;
    if (i < N_NODES) row_start[i] = ex;
    __syncthreads();
    if (tid == 0) carry_s += wsum[15];
    __syncthreads();
  }
  if (threadIdx.x == 0) row_start[N_NODES] = carry_s;
}

__global__ void k_scatter(const int* __restrict__ dst, const int* __restrict__ src,
                          const int* __restrict__ row_start, int* __restrict__ cursor,
                          int* __restrict__ eid, int* __restrict__ srcp) {
  int e = blockIdx.x * blockDim.x + threadIdx.x;
  if (e < N_EDGES) {
    int d = dst[e];
    int pos = row_start[d] + atomicAdd(&cursor[d], 1);
    eid[pos] = e;
    srcp[pos] = src[e];
  }
}

// ---------------- loop_attr: la[n][16] = mean of ea rows over in-edges ----------------
__global__ __launch_bounds__(256) void k_la(const float* __restrict__ ea,
                                            const int* __restrict__ eid,
                                            const int* __restrict__ row_start,
                                            float* __restrict__ la) {
  int node = blockIdx.x * 16 + (threadIdx.x >> 4);
  int k = threadIdx.x & 15;
  if (node >= N_NODES) return;
  int r0 = row_start[node], r1 = row_start[node + 1];
  float s = 0.f;
  for (int i = r0; i < r1; ++i) s += ea[(size_t)eid[i] * EDIM + k];
  la[node * EDIM + k] = s / (float)max(r1 - r0, 1);
}

// ---------------- conversions ----------------
__global__ void k_cvt_x(const float* __restrict__ x, u16* __restrict__ xb) {
  long t = (long)blockIdx.x * 256 + threadIdx.x;
  if (t >= (long)M_PAD * K1_PAD) return;
  int row = (int)(t / K1_PAD);
  int col = (int)(t % K1_PAD);
  float v = (row < N_NODES && col < F_INDIM) ? x[(size_t)row * F_INDIM + col] : 0.f;
  xb[t] = f2bf(v);
}

__global__ void k_cvt_wT(const float* __restrict__ W, u16* __restrict__ WT, int K, int N, int Kp) {
  int t = blockIdx.x * 256 + threadIdx.x;
  if (t >= N * Kp) return;
  int n = t / Kp, k = t % Kp;
  WT[t] = f2bf(k < K ? W[(size_t)k * N + n] : 0.f);
}

__global__ void k_cvt(const float* __restrict__ W, u16* __restrict__ O, int n) {
  int t = blockIdx.x * 256 + threadIdx.x;
  if (t < n) O[t] = f2bf(W[t]);
}

// ---------------- MFMA bf16 GEMM: C[M,Nd] = A[M,K] @ BT[Nd,K]^T ----------------
template <bool CF32>
__global__ __launch_bounds__(256) void gemm_mfma(const u16* __restrict__ A,
                                                 const u16* __restrict__ BT,
                                                 void* __restrict__ Cv, int M, int Nd, int K,
                                                 int lda, int ldb) {
  __shared__ u16 As[128 * 32];
  __shared__ u16 Bs[128 * 32];
  int tid = threadIdx.x;
  int lane = tid & 63;
  int wv = tid >> 6;
  int m_base = blockIdx.y * 128;
  int n_base = blockIdx.x * 128;
  int wrow = (wv >> 1) * 64;
  int wcol = (wv & 1) * 64;
  f32x4 acc[4][4];
#pragma unroll
  for (int i = 0; i < 4; ++i)
#pragma unroll
    for (int j = 0; j < 4; ++j)
#pragma unroll
      for (int r = 0; r < 4; ++r) acc[i][j][r] = 0.f;

  for (int k0 = 0; k0 < K; k0 += 32) {
    __syncthreads();
#pragma unroll
    for (int it = 0; it < 2; ++it) {
      int t = it * 256 + tid;
      int row = t >> 2;
      int kc = (t & 3) * 8;
      gl_lds16(A + (size_t)(m_base + row) * lda + k0 + kc, As + (size_t)(it * 256 + wv * 64) * 8);
      gl_lds16(BT + (size_t)(n_base + row) * ldb + k0 + kc, Bs + (size_t)(it * 256 + wv * 64) * 8);
    }
    __syncthreads();
    bf16x8 af[4], bfr[4];
#pragma unroll
    for (int i = 0; i < 4; ++i) {
      int r = wrow + i * 16 + (lane & 15);
      af[i] = *(const bf16x8*)(As + r * 32 + (lane >> 4) * 8);
    }
#pragma unroll
    for (int j = 0; j < 4; ++j) {
      int r = wcol + j * 16 + (lane & 15);
      bfr[j] = *(const bf16x8*)(Bs + r * 32 + (lane >> 4) * 8);
    }
#pragma unroll
    for (int i = 0; i < 4; ++i)
#pragma unroll
      for (int j = 0; j < 4; ++j)
        acc[i][j] = __builtin_amdgcn_mfma_f32_16x16x32_bf16(af[i], bfr[j], acc[i][j], 0, 0, 0);
  }
#pragma unroll
  for (int i = 0; i < 4; ++i) {
    int grow_base = m_base + wrow + i * 16 + (lane >> 4) * 4;
#pragma unroll
    for (int j = 0; j < 4; ++j) {
      int gcol = n_base + wcol + j * 16 + (lane & 15);
#pragma unroll
      for (int r = 0; r < 4; ++r) {
        int grow = grow_base + r;
        if (grow < M) {
          float v = acc[i][j][r];
          if (CF32)
            ((float*)Cv)[(size_t)grow * Nd + gcol] = v;
          else
            ((u16*)Cv)[(size_t)grow * Nd + gcol] = f2bf(v);
        }
      }
    }
  }
}

// ---------------- GAT layer 1 (D=64, concat) ----------------
// 256 thr/node, 2 cols/lane (float2 packed), wave covers 2 heads, width-32 reduce.
__global__ __launch_bounds__(256) void k_gat1(
    const u16* __restrict__ xlr, const float* __restrict__ ea, const float* __restrict__ We,
    const float* __restrict__ att, const float* __restrict__ bias, const int* __restrict__ srcp,
    const int* __restrict__ eid, const int* __restrict__ row_start, const float* __restrict__ la,
    u16* __restrict__ out) {
  int n = blockIdx.x;
  int tid = threadIdx.x;
  int col = tid * 2;  // cols [col, col+1], same head (heads are 64-wide)
  int r0 = row_start[n], r1 = row_start[n + 1];
  f32x2 Wc[EDIM];
#pragma unroll
  for (int k = 0; k < EDIM; ++k) Wc[k] = *(const f32x2*)(We + k * 512 + col);
  f32x2 av = *(const f32x2*)(att + col);
  f32x2 attA = 0.6f * av, attB = 0.4f * av;
  f32x2 xrd = bf2f2(*(const u32*)(xlr + (size_t)n * 1024 + 512 + col));
  f32x2 xls = bf2f2(*(const u32*)(xlr + (size_t)n * 1024 + col));

  auto escore = [&](int e, f32x2 xv) -> float {
    const float4* ea4 = (const float4*)(ea + (size_t)e * EDIM);
    float4 v0 = ea4[0], v1 = ea4[1], v2 = ea4[2], v3 = ea4[3];
    f32x2 t = v0.x * Wc[0];
    t = v0.y * Wc[1] + t;
    t = v0.z * Wc[2] + t;
    t = v0.w * Wc[3] + t;
    t = v1.x * Wc[4] + t;
    t = v1.y * Wc[5] + t;
    t = v1.z * Wc[6] + t;
    t = v1.w * Wc[7] + t;
    t = v2.x * Wc[8] + t;
    t = v2.y * Wc[9] + t;
    t = v2.z * Wc[10] + t;
    t = v2.w * Wc[11] + t;
    t = v3.x * Wc[12] + t;
    t = v3.y * Wc[13] + t;
    t = v3.z * Wc[14] + t;
    t = v3.w * Wc[15] + t;
    f32x2 z = xv + xrd + t;
    f32x2 q = attA * z + attB * abs2(z);
    return q.x + q.y;
  };

  f32x2 acc = {0.f, 0.f};
  float denom = 0.f;
  for (int i = r0; i < r1; i += 4) {
    int i1 = min(i + 1, r1 - 1), i2 = min(i + 2, r1 - 1), i3 = min(i + 3, r1 - 1);
    int e0 = __builtin_amdgcn_readfirstlane(eid[i]);
    int e1 = __builtin_amdgcn_readfirstlane(eid[i1]);
    int e2 = __builtin_amdgcn_readfirstlane(eid[i2]);
    int e3 = __builtin_amdgcn_readfirstlane(eid[i3]);
    int s0 = __builtin_amdgcn_readfirstlane(srcp[i]);
    int s1 = __builtin_amdgcn_readfirstlane(srcp[i1]);
    int s2 = __builtin_amdgcn_readfirstlane(srcp[i2]);
    int s3 = __builtin_amdgcn_readfirstlane(srcp[i3]);
    f32x2 x0 = bf2f2(*(const u32*)(xlr + (size_t)s0 * 1024 + col));
    f32x2 x1 = bf2f2(*(const u32*)(xlr + (size_t)s1 * 1024 + col));
    f32x2 x2 = bf2f2(*(const u32*)(xlr + (size_t)s2 * 1024 + col));
    f32x2 x3 = bf2f2(*(const u32*)(xlr + (size_t)s3 * 1024 + col));
    float p0 = escore(e0, x0);
    float p1 = escore(e1, x1);
    float p2 = escore(e2, x2);
    float p3 = escore(e3, x3);
    halfSum4(p0, p1, p2, p3);
    float w0 = __expf(p0), w1 = __expf(p1), w2 = __expf(p2), w3 = __expf(p3);
    if (i + 1 >= r1) w1 = 0.f;
    if (i + 2 >= r1) w2 = 0.f;
    if (i + 3 >= r1) w3 = 0.f;
    acc = w0 * x0 + acc;
    acc = w1 * x1 + acc;
    acc = w2 * x2 + acc;
    acc = w3 * x3 + acc;
    denom += (w0 + w1) + (w2 + w3);
  }
  // self loop via precomputed la
  f32x2 ee = {0.f, 0.f};
#pragma unroll
  for (int k = 0; k < EDIM; ++k) ee = la[n * EDIM + k] * Wc[k] + ee;
  f32x2 z = xls + xrd + ee;
  f32x2 q = attA * z + attB * abs2(z);
  float sc = halfSum(q.x + q.y);
  float w = __expf(sc);
  acc = w * xls + acc;
  denom += w;
  float inv = 1.f / denom;
  float t0 = tanhf(acc.x * inv + bias[col]);
  float t1 = tanhf(acc.y * inv + bias[col + 1]);
  u32 pack = (u32)f2bf(t0) | ((u32)f2bf(t1) << 16);
  *(u32*)(out + (size_t)n * 512 + col) = pack;
}

// ---------------- GAT layer 2 (D=128, mean heads) ----------------
// 256 thr/node, 4 cols/lane (2x float2 packed), wave covers 2 heads, width-32 reduce.
__global__ __launch_bounds__(256) void k_gat2(
    const u16* __restrict__ xlr, const float* __restrict__ ea, const float* __restrict__ We,
    const float* __restrict__ att, const float* __restrict__ bias, const int* __restrict__ srcp,
    const int* __restrict__ eid, const int* __restrict__ row_start, const float* __restrict__ la,
    u16* __restrict__ out) {
  int n = blockIdx.x;
  int tid = threadIdx.x;
  int lane = tid & 63;
  int wv = tid >> 6;
  int head = 2 * wv + (lane >> 5);
  int cih = (lane & 31) * 4;  // col within head
  int col = tid * 4;          // global col [col..col+3], within one head
  __shared__ float hsum[H_HEADS][DD2];
  int r0 = row_start[n], r1 = row_start[n + 1];
  f32x2 Wa[EDIM], Wb[EDIM];
#pragma unroll
  for (int k = 0; k < EDIM; ++k) {
    float4 t = *(const float4*)(We + k * 1024 + col);
    Wa[k].x = t.x;
    Wa[k].y = t.y;
    Wb[k].x = t.z;
    Wb[k].y = t.w;
  }
  float4 av4 = *(const float4*)(att + col);
  f32x2 attAa = {0.6f * av4.x, 0.6f * av4.y}, attBa = {0.4f * av4.x, 0.4f * av4.y};
  f32x2 attAb = {0.6f * av4.z, 0.6f * av4.w}, attBb = {0.4f * av4.z, 0.4f * av4.w};
  uint2 xru = *(const uint2*)(xlr + (size_t)n * 2048 + 1024 + col);
  uint2 xlu = *(const uint2*)(xlr + (size_t)n * 2048 + col);
  f32x2 xrda = bf2f2(xru.x), xrdb = bf2f2(xru.y);
  f32x2 xlsa = bf2f2(xlu.x), xlsb = bf2f2(xlu.y);

  auto escore = [&](int e, f32x2 xa, f32x2 xb) -> float {
    const float4* ea4 = (const float4*)(ea + (size_t)e * EDIM);
    float4 v0 = ea4[0], v1 = ea4[1], v2 = ea4[2], v3 = ea4[3];
    f32x2 ta = v0.x * Wa[0], tb = v0.x * Wb[0];
    ta = v0.y * Wa[1] + ta; tb = v0.y * Wb[1] + tb;
    ta = v0.z * Wa[2] + ta; tb = v0.z * Wb[2] + tb;
    ta = v0.w * Wa[3] + ta; tb = v0.w * Wb[3] + tb;
    ta = v1.x * Wa[4] + ta; tb = v1.x * Wb[4] + tb;
    ta = v1.y * Wa[5] + ta; tb = v1.y * Wb[5] + tb;
    ta = v1.z * Wa[6] + ta; tb = v1.z * Wb[6] + tb;
    ta = v1.w * Wa[7] + ta; tb = v1.w * Wb[7] + tb;
    ta = v2.x * Wa[8] + ta; tb = v2.x * Wb[8] + tb;
    ta = v2.y * Wa[9] + ta; tb = v2.y * Wb[9] + tb;
    ta = v2.z * Wa[10] + ta; tb = v2.z * Wb[10] + tb;
    ta = v2.w * Wa[11] + ta; tb = v2.w * Wb[11] + tb;
    ta = v3.x * Wa[12] + ta; tb = v3.x * Wb[12] + tb;
    ta = v3.y * Wa[13] + ta; tb = v3.y * Wb[13] + tb;
    ta = v3.z * Wa[14] + ta; tb = v3.z * Wb[14] + tb;
    ta = v3.w * Wa[15] + ta; tb = v3.w * Wb[15] + tb;
    f32x2 za = xa + xrda + ta;
    f32x2 zb = xb + xrdb + tb;
    f32x2 q = attAa * za + attBa * abs2(za);
    q = attAb * zb + q;
    q = attBb * abs2(zb) + q;
    return q.x + q.y;
  };

  f32x2 acca = {0.f, 0.f}, accb = {0.f, 0.f};
  float denom = 0.f;
  for (int i = r0; i < r1; i += 4) {
    int i1 = min(i + 1, r1 - 1), i2 = min(i + 2, r1 - 1), i3 = min(i + 3, r1 - 1);
    int e0 = __builtin_amdgcn_readfirstlane(eid[i]);
    int e1 = __builtin_amdgcn_readfirstlane(eid[i1]);
    int e2 = __builtin_amdgcn_readfirstlane(eid[i2]);
    int e3 = __builtin_amdgcn_readfirstlane(eid[i3]);
    int s0 = __builtin_amdgcn_readfirstlane(srcp[i]);
    int s1 = __builtin_amdgcn_readfirstlane(srcp[i1]);
    int s2 = __builtin_amdgcn_readfirstlane(srcp[i2]);
    int s3 = __builtin_amdgcn_readfirstlane(srcp[i3]);
    uint2 u0 = *(const uint2*)(xlr + (size_t)s0 * 2048 + col);
    uint2 u1 = *(const uint2*)(xlr + (size_t)s1 * 2048 + col);
    uint2 u2 = *(const uint2*)(xlr + (size_t)s2 * 2048 + col);
    uint2 u3 = *(const uint2*)(xlr + (size_t)s3 * 2048 + col);
    f32x2 x0a = bf2f2(u0.x), x0b = bf2f2(u0.y);
    f32x2 x1a = bf2f2(u1.x), x1b = bf2f2(u1.y);
    f32x2 x2a = bf2f2(u2.x), x2b = bf2f2(u2.y);
    f32x2 x3a = bf2f2(u3.x), x3b = bf2f2(u3.y);
    float p0 = escore(e0, x0a, x0b);
    float p1 = escore(e1, x1a, x1b);
    float p2 = escore(e2, x2a, x2b);
    float p3 = escore(e3, x3a, x3b);
    halfSum4(p0, p1, p2, p3);
    float w0 = __expf(p0), w1 = __expf(p1), w2 = __expf(p2), w3 = __expf(p3);
    if (i + 1 >= r1) w1 = 0.f;
    if (i + 2 >= r1) w2 = 0.f;
    if (i + 3 >= r1) w3 = 0.f;
    acca = w0 * x0a + acca; accb = w0 * x0b + accb;
    acca = w1 * x1a + acca; accb = w1 * x1b + accb;
    acca = w2 * x2a + acca; accb = w2 * x2b + accb;
    acca = w3 * x3a + acca; accb = w3 * x3b + accb;
    denom += (w0 + w1) + (w2 + w3);
  }
  // self loop
  f32x2 eea = {0.f, 0.f}, eeb = {0.f, 0.f};
#pragma unroll
  for (int k = 0; k < EDIM; ++k) {
    float lv = la[n * EDIM + k];
    eea = lv * Wa[k] + eea;
    eeb = lv * Wb[k] + eeb;
  }
  f32x2 za = xlsa + xrda + eea, zb = xlsb + xrdb + eeb;
  f32x2 q = attAa * za + attBa * abs2(za);
  q = attAb * zb + q;
  q = attBb * abs2(zb) + q;
  float sc = halfSum(q.x + q.y);
  float w = __expf(sc);
  acca = w * xlsa + acca;
  accb = w * xlsb + accb;
  denom += w;

  float inv = 1.f / denom;
  *(f32x2*)&hsum[head][cih] = acca * inv;
  *(f32x2*)&hsum[head][cih + 2] = accb * inv;
  __syncthreads();
  if (tid < DD2) {
    float s = 0.f;
#pragma unroll
    for (int hh = 0; hh < H_HEADS; ++hh) s += hsum[hh][tid];
    out[(size_t)n * DD2 + tid] = f2bf(tanhf(s * 0.125f + bias[tid]));
  }
}

// ---------------- LSTM (single step, h0=c0=0) + FC ----------------
__global__ __launch_bounds__(128) void k_lstm(const float* __restrict__ gates,
                                              const float* __restrict__ b_ih,
                                              const float* __restrict__ b_hh,
                                              const float* __restrict__ fcW,
                                              const float* __restrict__ fcb,
                                              float* __restrict__ out) {
  int n = blockIdx.x;
  int j = threadIdx.x;
  __shared__ float gs[128];
  gs[j] = gates[(size_t)n * 128 + j] + b_ih[j] + b_hh[j];
  __syncthreads();
  if (j < 32) {
    float iv = gs[j], gv = gs[64 + j], ov = gs[96 + j];
    float c = (1.f / (1.f + __expf(-iv))) * tanhf(gv);
    float hd = (1.f / (1.f + __expf(-ov))) * tanhf(c);
    float p = hd * fcW[j];
#pragma unroll
    for (int off = 16; off > 0; off >>= 1) p += __shfl_down(p, off, 32);
    if (j == 0) out[n] = p + fcb[0];
  }
}

extern "C" void kernel_launch(void* const* d_in, const int* in_sizes, int n_in, void* d_out,
                              int out_size, void* d_ws, size_t ws_size, hipStream_t stream) {
  const float* x = (const float*)d_in[0];
  const int* ei = (const int*)d_in[1];
  const float* ea = (const float*)d_in[2];
  const float* Wl1 = (const float*)d_in[3];
  const float* Wr1 = (const float*)d_in[4];
  const float* We1 = (const float*)d_in[5];
  const float* att1 = (const float*)d_in[6];
  const float* b1 = (const float*)d_in[7];
  const float* Wl2 = (const float*)d_in[8];
  const float* Wr2 = (const float*)d_in[9];
  const float* We2 = (const float*)d_in[10];
  const float* att2 = (const float*)d_in[11];
  const float* b2 = (const float*)d_in[12];
  const float* W_ih = (const float*)d_in[13];
  const float* b_ih = (const float*)d_in[15];
  const float* b_hh = (const float*)d_in[16];
  const float* fcW = (const float*)d_in[17];
  const float* fcb = (const float*)d_in[18];
  float* out = (float*)d_out;
  const int* srcA = ei;
  const int* dstA = ei + N_EDGES;

  char* ws = (char*)d_ws;
  const size_t OFF_XBF = (size_t)N_NODES * 1024 * 2;            // 102,400,000
  const size_t OFF_H1 = (size_t)N_NODES * 2048 * 2;             // 204,800,000
  const size_t OFF_GATES = OFF_H1 + (size_t)M_PAD * 128 * 2;    // 217,612,288
  size_t off = OFF_H1 + (size_t)M_PAD * 512 * 2;                // 256,049,152
  auto take = [&](size_t bytes) -> char* {
    off = (off + 255) & ~(size_t)255;
    char* p = ws + off;
    off += bytes;
    return p;
  };
  u16* W1T = (u16*)take((size_t)1024 * K1_PAD * 2);  // [Wl1T ; Wr1T]
  u16* W2T = (u16*)take((size_t)2048 * 512 * 2);     // [Wl2T ; Wr2T]
  u16* WihB = (u16*)take((size_t)128 * 128 * 2);
  int* deg = (int*)take((size_t)N_NODES * 4);
  int* cursor = (int*)take((size_t)N_NODES * 4);
  int* row_start = (int*)take((size_t)(N_NODES + 1) * 4);
  int* eid = (int*)take((size_t)N_EDGES * 4);
  int* srcp = (int*)take((size_t)N_EDGES * 4);
  float* la = (float*)take((size_t)N_NODES * EDIM * 4);

  if (off > ws_size) {
    k_zero<<<(out_size + 255) / 256, 256, 0, stream>>>(out, out_size);
    return;
  }

  u16* xlr1 = (u16*)ws;
  u16* xbf = (u16*)(ws + OFF_XBF);
  u16* xlr2 = (u16*)ws;
  u16* h1 = (u16*)(ws + OFF_H1);
  u16* h2 = (u16*)(ws + OFF_H1);
  float* gates = (float*)(ws + OFF_GATES);

  hipMemsetAsync(deg, 0, (size_t)N_NODES * 4, stream);
  hipMemsetAsync(cursor, 0, (size_t)N_NODES * 4, stream);
  k_hist<<<(N_EDGES + 255) / 256, 256, 0, stream>>>(dstA, deg);
  k_scan<<<1, 1024, 0, stream>>>(deg, row_start);
  k_scatter<<<(N_EDGES + 255) / 256, 256, 0, stream>>>(dstA, srcA, row_start, cursor, eid, srcp);
  k_la<<<(N_NODES + 15) / 16, 256, 0, stream>>>(ea, eid, row_start, la);

  {
    long tot = (long)M_PAD * K1_PAD;
    k_cvt_x<<<(unsigned)((tot + 255) / 256), 256, 0, stream>>>(x, xbf);
    k_cvt_wT<<<(512 * K1_PAD + 255) / 256, 256, 0, stream>>>(Wl1, W1T, F_INDIM, 512, K1_PAD);
    k_cvt_wT<<<(512 * K1_PAD + 255) / 256, 256, 0, stream>>>(Wr1, W1T + (size_t)512 * K1_PAD,
                                                             F_INDIM, 512, K1_PAD);
    k_cvt_wT<<<(1024 * 512 + 255) / 256, 256, 0, stream>>>(Wl2, W2T, 512, 1024, 512);
    k_cvt_wT<<<(1024 * 512 + 255) / 256, 256, 0, stream>>>(Wr2, W2T + (size_t)1024 * 512, 512,
                                                           1024, 512);
    k_cvt<<<(128 * 128 + 255) / 256, 256, 0, stream>>>(W_ih, WihB, 128 * 128);
  }

  const int MB = M_PAD / 128;  // 391
  gemm_mfma<false><<<dim3(1024 / 128, MB), 256, 0, stream>>>(xbf, W1T, xlr1, N_NODES, 1024,
                                                             K1_PAD, K1_PAD, K1_PAD);
  k_gat1<<<N_NODES, 256, 0, stream>>>(xlr1, ea, We1, att1, b1, srcp, eid, row_start, la, h1);

  gemm_mfma<false><<<dim3(2048 / 128, MB), 256, 0, stream>>>(h1, W2T, xlr2, N_NODES, 2048, 512,
                                                             512, 512);
  k_gat2<<<N_NODES, 256, 0, stream>>>(xlr2, ea, We2, att2, b2, srcp, eid, row_start, la, h2);

  gemm_mfma<true><<<dim3(1, MB), 256, 0, stream>>>(h2, WihB, gates, N_NODES, 128, 128, 128, 128);
  k_lstm<<<N_NODES, 128, 0, stream>>>(gates, b_ih, b_hh, fcW, fcb, out);
}